// Round 10
// baseline (17782.350 us; speedup 1.0000x reference)
//
#include <hip/hip_runtime.h>
#include <hip/hip_bf16.h>

// Jordan RNN restructured:
//   Wc = Wyh @ Wout  [H,H]
//   pre[b,t,:] = emb@Whx^T + bhx + byh + (t==0 ? last_logits@Wyh^T : Wyh@bout)
//   scan: h_t = tanh(pre_t + h_{t-1} @ Wc^T)     (per-batch independent)
//   y_t  = h_t @ Wout^T + bout                    (time-parallel epilogue GEMM)
//
// Scan (this round): SAME-XCD paired N-split. Pair p uses blocks (p, p+8):
// with the default round-robin bid%8 -> XCD mapping both blocks land on ONE
// XCD, so the per-step h exchange rides the shared (coherent) per-XCD L2.
// R7's version of this regressed because pairs (2p,2p+1) were CROSS-XCD:
// FETCH ballooned +67MB (partner h via HBM) and the agent fence forced L2
// writebacks. Same protocol (proven correct even cross-XCD), new placement.
//   - side s computes h cols [256s,256s+256) for its pair's 16 batches
//   - Wc B-frags FULLY AGPR-resident (16kt x 2nt x 4regs = 128 AGPR/wave)
//   - own-half h via 16KB LDS dbuf; partner half read as A-frags from global
//   - per-step: fence -> barrier -> tid0 release-flag; partner acquire-spins
//
// d_out row layout (1024 u16 per [b,t] row), in-place through all phases:
//   u16 [0,256)+[768,1024) : pre as bf16, permuted (P1 writes; scan reads u16x2)
//   u16 [256,768)          : h as bf16 (scan writes, P3 reads + exchange)
//   P3 overwrites the whole row with fp32 y.

#define NB 64
#define NT 2048
#define ND 512
#define NH 512
#define NO 512
#define TH (NT * NH)

typedef float f32x4 __attribute__((ext_vector_type(4)));
typedef __bf16 bf16x8 __attribute__((ext_vector_type(8)));
typedef unsigned short u16x8 __attribute__((ext_vector_type(8)));
typedef unsigned short u16x2 __attribute__((ext_vector_type(2)));

__device__ __forceinline__ unsigned short f2bf(float x) {
  unsigned u = __builtin_bit_cast(unsigned, x);
  u += 0x7FFFu + ((u >> 16) & 1u);               // RNE
  return (unsigned short)(u >> 16);
}
__device__ __forceinline__ float bf2f(unsigned short u) {
  return __builtin_bit_cast(float, (unsigned)u << 16);
}
__device__ __forceinline__ bf16x8 ld_frag(const unsigned short* p) {
  u16x8 r = *(const u16x8*)p;
  return __builtin_bit_cast(bf16x8, r);
}
__device__ __forceinline__ f32x4 ld_frag4(const unsigned short* p) {
  return *(const f32x4*)p;
}
// tanh via hardware exp2/rcp: abs err ~1e-6, inf-safe.
__device__ __forceinline__ float fast_tanh(float x) {
  float ax = __builtin_fabsf(x);
  float e = __builtin_amdgcn_exp2f(ax * 2.8853900817779268f);  // e^(2|x|)
  float r = 1.0f - 2.0f * __builtin_amdgcn_rcpf(e + 1.0f);
  return __builtin_copysignf(r, x);
}

// ---------------- prep kernels ----------------

// also re-initializes the scan sync flags every launch (deterministic replay)
__global__ void k_bias(const float* __restrict__ Wyh, const float* __restrict__ bout,
                       const float* __restrict__ bhx, const float* __restrict__ byh,
                       float* bias_t0, float* bias_t, int* flags) {
  int j = threadIdx.x;
  if (j < 256) flags[j] = -1;
  const float* row = Wyh + j * NO;
  float acc = 0.f;
  for (int o = 0; o < NO; ++o) acc += row[o] * bout[o];
  bias_t0[j] = bhx[j] + byh[j];
  bias_t[j]  = bhx[j] + byh[j] + acc;
}

__global__ void k_z0(const float* __restrict__ ll, const float* __restrict__ Wyh,
                     float* z0) {
  int b = blockIdx.x, j = threadIdx.x;
  const float* row = Wyh + j * NO;
  const float* lr = ll + b * NO;
  float acc = 0.f;
  for (int o = 0; o < NO; ++o) acc += lr[o] * row[o];
  z0[b * NH + j] = acc;
}

__global__ void k_wc(const float* __restrict__ Wyh, const float* __restrict__ Wout,
                     float* Wc) {
  int j = blockIdx.x, k = threadIdx.x;
  float acc = 0.f;
  for (int o = 0; o < NO; ++o) acc += Wyh[j * NO + o] * Wout[o * NH + k];
  Wc[j * NH + k] = acc;
}

// Build MFMA B-operand fragments for Bm = src^T (src is [N=512 rows][K=512 cols]).
// Fragment for 16x16x32: lane l holds B[kt*32 + (l>>4)*8 + i][nt*16 + (l&15)], i=0..7.
__global__ void k_frag(const float* __restrict__ src, unsigned short* __restrict__ dst) {
  int gid = blockIdx.x * 256 + threadIdx.x;  // 32768 total
  int lane = gid & 63, tidx = gid >> 6;
  int nt = tidx & 31, kt = tidx >> 5;
  const float* s = src + (size_t)(nt * 16 + (lane & 15)) * 512 + kt * 32 + (lane >> 4) * 8;
  unsigned short* d = dst + (size_t)gid * 8;
#pragma unroll
  for (int i = 0; i < 8; ++i) d[i] = f2bf(s[i]);
}

// permuted pre u16 index within a 1024-u16 row, for hidden col c:
// region base = (c>>7)*128 + ((c>>8)<<9); within: (c&15)*8 + ((c>>4)&7)
// -> regions [0,128),[128,256),[768,896),[896,1024); h keeps [256,768).
__device__ __forceinline__ int pre_idx(int col) {
  int w = col >> 7;
  return w * 128 + ((w >> 1) << 9) + (col & 15) * 8 + ((col >> 4) & 7);
}

// ---------------- big GEMM (P1 and P3) ----------------
// MODE 0 (P1): A fp32 (emb); out = bf16 pre in permuted u16 layout
// MODE 1 (P3): A bf16 h at u16 [256,768) of each row; out = fp32 y (full row);
//              in-place (A aliases out); t==T-1 rows -> last[]
template <int MODE>
__global__ __launch_bounds__(512) void k_gemm(
    const void* __restrict__ Ain, const unsigned short* __restrict__ fragB,
    float* __restrict__ out, const float* __restrict__ bias_t0,
    const float* __restrict__ bias_t, const float* __restrict__ z0,
    const float* __restrict__ bout, float* __restrict__ last) {
  __shared__ __align__(16) unsigned short a_lds[64 * 512];  // 64KB, XOR-swizzled bf16
  int tid = threadIdx.x;
  long bt0 = (long)blockIdx.x * 64;

  if (MODE == 0) {
    const float* A = (const float*)Ain;
#pragma unroll
    for (int it = 0; it < 16; ++it) {
      int chunk = it * 512 + tid;
      int r = chunk >> 7, c4 = chunk & 127;
      float4 v = ((const float4*)A)[(bt0 + r) * 128 + c4];
      int idx = (r * 512 + c4 * 4) ^ ((r & 7) << 3);
      unsigned short* p = &a_lds[idx];
      p[0] = f2bf(v.x); p[1] = f2bf(v.y); p[2] = f2bf(v.z); p[3] = f2bf(v.w);
    }
  } else {
    const unsigned short* A = (const unsigned short*)Ain;
#pragma unroll
    for (int it = 0; it < 8; ++it) {
      int chunk = it * 512 + tid;           // 4096 chunks of 8 u16
      int r = chunk >> 6, c8 = chunk & 63;
      u16x8 v = *(const u16x8*)(A + (size_t)(bt0 + r) * 1024 + 256 + c8 * 8);
      int idx = (r * 512 + c8 * 8) ^ ((r & 7) << 3);
      *(u16x8*)&a_lds[idx] = v;
    }
  }
  __syncthreads();

  int wave = tid >> 6, lane = tid & 63;
  int r0 = (wave & 3) * 16, c0 = (wave >> 2) * 256;
  f32x4 acc[16];
#pragma unroll
  for (int n = 0; n < 16; ++n) acc[n] = (f32x4){0.f, 0.f, 0.f, 0.f};
  int arow = r0 + (lane & 15);

  for (int kt = 0; kt < 16; ++kt) {
    int aidx = (arow * 512 + kt * 32 + (lane >> 4) * 8) ^ ((arow & 7) << 3);
    bf16x8 a = ld_frag(&a_lds[aidx]);
    const unsigned short* bp = fragB + ((size_t)(kt * 32 + (c0 >> 4)) * 64 + lane) * 8;
#pragma unroll
    for (int n = 0; n < 16; ++n) {
      bf16x8 b = ld_frag(bp + (size_t)n * 512);
      acc[n] = __builtin_amdgcn_mfma_f32_16x16x32_bf16(a, b, acc[n], 0, 0, 0);
    }
  }

#pragma unroll
  for (int n = 0; n < 16; ++n) {
    int col = c0 + n * 16 + (lane & 15);
#pragma unroll
    for (int reg = 0; reg < 4; ++reg) {
      long row = bt0 + r0 + (lane >> 4) * 4 + reg;
      float v = acc[n][reg];
      if (MODE == 0) {
        int t = (int)(row & (NT - 1));
        long b = row >> 11;
        v += (t == 0) ? (bias_t0[col] + z0[b * NH + col]) : bias_t[col];
        ((unsigned short*)out)[row * 1024 + pre_idx(col)] = f2bf(v);
      } else {
        v += bout[col];
        out[row * 512 + col] = v;
        if ((row & (NT - 1)) == NT - 1) last[(row >> 11) * 512 + col] = v;
      }
    }
  }
}

// ---------------- sequential scan (same-XCD paired N-split) ----------------
// grid 12 x 512. Active: bid&7 < 4. Pair p = bid&7 uses blocks p (side 0) and
// p+8 (side 1) -> same XCD under bid%8 round-robin. Own h half via LDS dbuf;
// partner half via global h-store (shared L2) + per-step flag handshake.
__global__ __launch_bounds__(512, 2) void k_scan(float* __restrict__ buf,
                                                 const unsigned short* __restrict__ fragWc,
                                                 int* __restrict__ flags) {
  const int bid = blockIdx.x;
  if ((bid & 7) >= 4) return;          // idle filler blocks (XCDs 4..7)
  const int pair = bid & 7;            // 0..3
  const int side = bid >> 3;           // blocks 0-3 -> side 0, 8-11 -> side 1

  __shared__ __align__(16) unsigned short h_lds[2][16 * 256];  // 16KB

  unsigned short* hbuf = (unsigned short*)buf;
  const int tid = threadIdx.x;
  const int wave = tid >> 6, lane = tid & 63;
  const int arow = lane & 15, bb = lane >> 4;
  const int b0 = pair * 16;
  const int Cs = side * 256, Cp = 256 - Cs;
  const int colbase = Cs + wave * 32;              // this wave's 2 nt groups
  const int w128 = colbase >> 7;
  const int region = w128 * 128 + ((w128 >> 1) << 9);
  const int poff = region + arow * 8 + ((colbase >> 4) & 7);
  const int swz = (arow & 7) << 3;

  int* flagO = flags + (pair * 2 + side) * 32;
  int* flagP = flags + (pair * 2 + (1 - side)) * 32;

  // ---- Wc B-frags fully AGPR-resident: g<8 own kt (k in own cols), g>=8
  //      partner kt. 16 x 2 x 4 = 128 AGPR/wave ("+a" pin held in R9:
  //      FETCH halved when it engaged).
  f32x4 br[16][2];
#pragma unroll
  for (int g = 0; g < 16; ++g) {
    int ktg = (g < 8) ? (8 * side + g) : (8 * (1 - side) + (g - 8));
#pragma unroll
    for (int n = 0; n < 2; ++n)
      br[g][n] =
          ld_frag4(fragWc + ((size_t)(ktg * 32 + (colbase >> 4) + n) * 64 + lane) * 8);
  }
#pragma unroll
  for (int g = 0; g < 16; ++g)
#pragma unroll
    for (int n = 0; n < 2; ++n) asm volatile("" : "+a"(br[g][n]));

  // ---- t = 0: h0 = tanh(pre0) on own cols (pre/h u16 regions disjoint) ----
  u16x2 pr[4];
#pragma unroll
  for (int r = 0; r < 4; ++r)
    pr[r] = *(const u16x2*)(hbuf + (size_t)(b0 + bb * 4 + r) * (size_t)(NT * 1024) + poff);
#pragma unroll
  for (int r = 0; r < 4; ++r)
#pragma unroll
    for (int n = 0; n < 2; ++n) {
      float h = fast_tanh(bf2f(pr[r][n]));
      unsigned short hb = f2bf(h);
      int b = bb * 4 + r;
      int cl = wave * 32 + n * 16 + arow;          // col local in [0,256)
      hbuf[(size_t)(b0 + b) * (size_t)(NT * 1024) + 256 + Cs + cl] = hb;
      h_lds[0][(b * 256 + cl) ^ ((b & 7) << 3)] = hb;
    }

  // per-lane pointers at the t=1 row
  const unsigned short* pPa =
      hbuf + (size_t)(b0 + arow) * (size_t)(NT * 1024) + 256 + Cp + bb * 8;  // h(t-1) row
  const unsigned short* pPre[4];
  unsigned short* pSt[4];
#pragma unroll
  for (int r = 0; r < 4; ++r) {
    size_t base = (size_t)(b0 + bb * 4 + r) * (size_t)(NT * 1024) + 1024;
    pPre[r] = hbuf + base + poff;
    pSt[r]  = hbuf + base + 256 + Cs + wave * 32 + arow;
  }
  // preload pre(t=1)
#pragma unroll
  for (int r = 0; r < 4; ++r) pr[r] = *(const u16x2*)pPre[r];

  // publish h(0): per-thread fence (drains own stores), all-wave barrier,
  // single release flag. Also makes h_lds[0] visible to all waves.
  __threadfence();
  __syncthreads();
  if (tid == 0) __hip_atomic_store(flagO, 0, __ATOMIC_RELEASE, __HIP_MEMORY_SCOPE_AGENT);

#pragma unroll 1
  for (int t = 1; t < NT; ++t) {
    // 0) wait for partner h(t-1) (same-XCD L2 poll; usually already posted)
    {
      const int want = t - 1;
      while (__hip_atomic_load(flagP, __ATOMIC_ACQUIRE, __HIP_MEMORY_SCOPE_AGENT) < want)
        __builtin_amdgcn_s_sleep(1);
    }

    // 1) issue partner A-frag loads (8 x b128; latency hides under own MFMA)
    bf16x8 pa[8];
#pragma unroll
    for (int kl = 0; kl < 8; ++kl) pa[kl] = ld_frag(pPa + kl * 32);

    // 2) acc <- pre(t); then issue pre(t+1) loads (after partner loads in the
    //    in-order VMEM queue)
    f32x4 acc[2];
#pragma unroll
    for (int n = 0; n < 2; ++n)
#pragma unroll
      for (int r = 0; r < 4; ++r) acc[n][r] = bf2f(pr[r][n]);
    if (t < NT - 1) {
#pragma unroll
      for (int r = 0; r < 4; ++r) {
        pPre[r] += 1024;
        pr[r] = *(const u16x2*)pPre[r];
      }
    }

    // 3) own-half MFMA: A from h_lds (written + barriered last step)
    const unsigned short* hs = h_lds[(t - 1) & 1];
#pragma unroll
    for (int kl = 0; kl < 8; ++kl) {
      bf16x8 a = ld_frag(hs + ((arow * 256 + kl * 32 + bb * 8) ^ swz));
      acc[0] = __builtin_amdgcn_mfma_f32_16x16x32_bf16(
          a, __builtin_bit_cast(bf16x8, br[kl][0]), acc[0], 0, 0, 0);
      acc[1] = __builtin_amdgcn_mfma_f32_16x16x32_bf16(
          a, __builtin_bit_cast(bf16x8, br[kl][1]), acc[1], 0, 0, 0);
    }
    // 4) partner-half MFMA: A direct from the global loads
#pragma unroll
    for (int kl = 0; kl < 8; ++kl) {
      acc[0] = __builtin_amdgcn_mfma_f32_16x16x32_bf16(
          pa[kl], __builtin_bit_cast(bf16x8, br[8 + kl][0]), acc[0], 0, 0, 0);
      acc[1] = __builtin_amdgcn_mfma_f32_16x16x32_bf16(
          pa[kl], __builtin_bit_cast(bf16x8, br[8 + kl][1]), acc[1], 0, 0, 0);
    }

    // 5) epilogue: tanh -> bf16 -> global (P3 input + exchange) + LDS
    unsigned short* hdst = h_lds[t & 1];
#pragma unroll
    for (int n = 0; n < 2; ++n)
#pragma unroll
      for (int r = 0; r < 4; ++r) {
        int b = bb * 4 + r;
        float h = fast_tanh(acc[n][r]);
        unsigned short hb = f2bf(h);
        pSt[r][n * 16] = hb;
        hdst[(b * 256 + wave * 32 + n * 16 + arow) ^ ((b & 7) << 3)] = hb;
      }
#pragma unroll
    for (int r = 0; r < 4; ++r) pSt[r] += 1024;
    pPa += 1024;

    // 6) publish h(t): fence (per-thread store drain) -> barrier -> release
    __threadfence();
    __syncthreads();
    if (tid == 0) __hip_atomic_store(flagO, t, __ATOMIC_RELEASE, __HIP_MEMORY_SCOPE_AGENT);
  }
}

// ---------------- launch ----------------
extern "C" void kernel_launch(void* const* d_in, const int* in_sizes, int n_in,
                              void* d_out, int out_size, void* d_ws, size_t ws_size,
                              hipStream_t stream) {
  const float* emb  = (const float*)d_in[0];
  const float* ll   = (const float*)d_in[1];
  const float* Whx  = (const float*)d_in[2];
  const float* bhx  = (const float*)d_in[3];
  const float* Wyh  = (const float*)d_in[4];
  const float* byh  = (const float*)d_in[5];
  const float* Wout = (const float*)d_in[6];
  const float* bout = (const float*)d_in[7];

  float* buf  = (float*)d_out;                       // [B*T, 512] pre/h -> y (in place)
  float* last = buf + (size_t)NB * NT * NO;          // [B, O] tail

  char* ws = (char*)d_ws;                            // ~2.7 MB used
  unsigned short* fragWhx  = (unsigned short*)ws;                         // 512KB
  unsigned short* fragWc   = (unsigned short*)(ws + (512 * 512 * 2));     // 512KB
  unsigned short* fragWout = (unsigned short*)(ws + 2 * (512 * 512 * 2)); // 512KB
  float* z0      = (float*)(ws + 3 * (512 * 512 * 2));                    // 128KB
  float* bias_t0 = z0 + NB * NH;
  float* bias_t  = bias_t0 + NH;
  float* Wc_f32  = bias_t + NH;                                           // 1MB
  int*   flags   = (int*)(Wc_f32 + 512 * 512);                            // 1KB

  k_bias<<<1, 512, 0, stream>>>(Wyh, bout, bhx, byh, bias_t0, bias_t, flags);
  k_z0<<<64, 512, 0, stream>>>(ll, Wyh, z0);
  k_wc<<<512, 512, 0, stream>>>(Wyh, Wout, Wc_f32);
  k_frag<<<128, 256, 0, stream>>>(Whx, fragWhx);     // Bm[d][j] = Whx[j][d]
  k_frag<<<128, 256, 0, stream>>>(Wc_f32, fragWc);   // Bm[k][j] = Wc[j][k]
  k_frag<<<128, 256, 0, stream>>>(Wout, fragWout);   // Bm[k][o] = Wout[o][k]

  // P1: pre = emb @ Whx^T + biases -> bf16 permuted layout (t==0 rows get z0)
  k_gemm<0><<<2048, 512, 0, stream>>>(emb, fragWhx, buf, bias_t0, bias_t, z0, bout, last);
  // P2: sequential scan (4 same-XCD pairs), h (bf16) into u16 [256,768)
  k_scan<<<12, 512, 0, stream>>>(buf, fragWc, flags);
  // P3: y = h @ Wout^T + bout, in place; also fills `last`
  k_gemm<1><<<2048, 512, 0, stream>>>(buf, fragWout, buf, bias_t0, bias_t, z0, bout, last);
}

// Round 11
// 15430.597 us; speedup vs baseline: 1.1524x; 1.1524x over previous
//
#include <hip/hip_runtime.h>
#include <hip/hip_bf16.h>

// Jordan RNN restructured:
//   Wc = Wyh @ Wout  [H,H]
//   pre[b,t,:] = emb@Whx^T + bhx + byh + (t==0 ? last_logits@Wyh^T : Wyh@bout)
//   scan: h_t = tanh(pre_t + h_{t-1} @ Wc^T)     (per-batch independent)
//   y_t  = h_t @ Wout^T + bout                    (time-parallel epilogue GEMM)
//
// Scan: 4 WGs x 512 threads (8 waves, 2/SIMD), NO cross-WG sync (R7+R10 both
// proved per-step global exchange regresses: fence-induced L2 writebacks +
// partner traffic doubled FETCH). Wc is FULLY AGPR-RESIDENT:
//   ba[16][4] = 16 kt-groups x 4 nt x 4 regs = 256 AGPR/wave, "+a"-pinned
//   (the pin mechanism that verifiably engaged in R9 -- FETCH halved).
// gfx950 unified RF: 1024 slots/SIMD; 256 AGPR + ~120 arch = ~376/wave fits
// 2 waves/SIMD. Zero Wc traffic, zero wc_lds; LDS = 32KB h dbuf only.
// Per step: barrier -> 16 x {ds_read A-frag, 4 MFMA} -> tanh epilogue -> barrier.
//
// d_out row layout (1024 u16 per [b,t] row), in-place through all phases:
//   u16 [0,256)+[768,1024) : pre as bf16, permuted (P1 writes; scan reads u16x4)
//   u16 [256,768)          : h as bf16 (scan writes, P3 reads)
//   P3 overwrites the whole row with fp32 y.

#define NB 64
#define NT 2048
#define ND 512
#define NH 512
#define NO 512
#define TH (NT * NH)

typedef float f32x4 __attribute__((ext_vector_type(4)));
typedef __bf16 bf16x8 __attribute__((ext_vector_type(8)));
typedef unsigned short u16x8 __attribute__((ext_vector_type(8)));
typedef unsigned short u16x4 __attribute__((ext_vector_type(4)));

__device__ __forceinline__ unsigned short f2bf(float x) {
  unsigned u = __builtin_bit_cast(unsigned, x);
  u += 0x7FFFu + ((u >> 16) & 1u);               // RNE
  return (unsigned short)(u >> 16);
}
__device__ __forceinline__ float bf2f(unsigned short u) {
  return __builtin_bit_cast(float, (unsigned)u << 16);
}
__device__ __forceinline__ bf16x8 ld_frag(const unsigned short* p) {
  u16x8 r = *(const u16x8*)p;
  return __builtin_bit_cast(bf16x8, r);
}
__device__ __forceinline__ f32x4 ld_frag4(const unsigned short* p) {
  return *(const f32x4*)p;
}
// tanh via hardware exp2/rcp: abs err ~1e-6, inf-safe.
__device__ __forceinline__ float fast_tanh(float x) {
  float ax = __builtin_fabsf(x);
  float e = __builtin_amdgcn_exp2f(ax * 2.8853900817779268f);  // e^(2|x|)
  float r = 1.0f - 2.0f * __builtin_amdgcn_rcpf(e + 1.0f);
  return __builtin_copysignf(r, x);
}

// ---------------- prep kernels ----------------

__global__ void k_bias(const float* __restrict__ Wyh, const float* __restrict__ bout,
                       const float* __restrict__ bhx, const float* __restrict__ byh,
                       float* bias_t0, float* bias_t) {
  int j = threadIdx.x;
  const float* row = Wyh + j * NO;
  float acc = 0.f;
  for (int o = 0; o < NO; ++o) acc += row[o] * bout[o];
  bias_t0[j] = bhx[j] + byh[j];
  bias_t[j]  = bhx[j] + byh[j] + acc;
}

__global__ void k_z0(const float* __restrict__ ll, const float* __restrict__ Wyh,
                     float* z0) {
  int b = blockIdx.x, j = threadIdx.x;
  const float* row = Wyh + j * NO;
  const float* lr = ll + b * NO;
  float acc = 0.f;
  for (int o = 0; o < NO; ++o) acc += lr[o] * row[o];
  z0[b * NH + j] = acc;
}

__global__ void k_wc(const float* __restrict__ Wyh, const float* __restrict__ Wout,
                     float* Wc) {
  int j = blockIdx.x, k = threadIdx.x;
  float acc = 0.f;
  for (int o = 0; o < NO; ++o) acc += Wyh[j * NO + o] * Wout[o * NH + k];
  Wc[j * NH + k] = acc;
}

// Build MFMA B-operand fragments for Bm = src^T (src is [N=512 rows][K=512 cols]).
// Fragment for 16x16x32: lane l holds B[kt*32 + (l>>4)*8 + i][nt*16 + (l&15)], i=0..7.
__global__ void k_frag(const float* __restrict__ src, unsigned short* __restrict__ dst) {
  int gid = blockIdx.x * 256 + threadIdx.x;  // 32768 total
  int lane = gid & 63, tidx = gid >> 6;
  int nt = tidx & 31, kt = tidx >> 5;
  const float* s = src + (size_t)(nt * 16 + (lane & 15)) * 512 + kt * 32 + (lane >> 4) * 8;
  unsigned short* d = dst + (size_t)gid * 8;
#pragma unroll
  for (int i = 0; i < 8; ++i) d[i] = f2bf(s[i]);
}

// permuted pre u16 index within a 1024-u16 row, for hidden col c:
// region base = (c>>7)*128 + ((c>>8)<<9); within: (c&15)*8 + ((c>>4)&7)
// -> regions [0,128),[128,256),[768,896),[896,1024); h keeps [256,768).
__device__ __forceinline__ int pre_idx(int col) {
  int w = col >> 7;
  return w * 128 + ((w >> 1) << 9) + (col & 15) * 8 + ((col >> 4) & 7);
}

// ---------------- big GEMM (P1 and P3) ----------------
// MODE 0 (P1): A fp32 (emb); out = bf16 pre in permuted u16 layout
// MODE 1 (P3): A bf16 h at u16 [256,768) of each row; out = fp32 y (full row);
//              in-place (A aliases out); t==T-1 rows -> last[]
template <int MODE>
__global__ __launch_bounds__(512) void k_gemm(
    const void* __restrict__ Ain, const unsigned short* __restrict__ fragB,
    float* __restrict__ out, const float* __restrict__ bias_t0,
    const float* __restrict__ bias_t, const float* __restrict__ z0,
    const float* __restrict__ bout, float* __restrict__ last) {
  __shared__ __align__(16) unsigned short a_lds[64 * 512];  // 64KB, XOR-swizzled bf16
  int tid = threadIdx.x;
  long bt0 = (long)blockIdx.x * 64;

  if (MODE == 0) {
    const float* A = (const float*)Ain;
#pragma unroll
    for (int it = 0; it < 16; ++it) {
      int chunk = it * 512 + tid;
      int r = chunk >> 7, c4 = chunk & 127;
      float4 v = ((const float4*)A)[(bt0 + r) * 128 + c4];
      int idx = (r * 512 + c4 * 4) ^ ((r & 7) << 3);
      unsigned short* p = &a_lds[idx];
      p[0] = f2bf(v.x); p[1] = f2bf(v.y); p[2] = f2bf(v.z); p[3] = f2bf(v.w);
    }
  } else {
    const unsigned short* A = (const unsigned short*)Ain;
#pragma unroll
    for (int it = 0; it < 8; ++it) {
      int chunk = it * 512 + tid;           // 4096 chunks of 8 u16
      int r = chunk >> 6, c8 = chunk & 63;
      u16x8 v = *(const u16x8*)(A + (size_t)(bt0 + r) * 1024 + 256 + c8 * 8);
      int idx = (r * 512 + c8 * 8) ^ ((r & 7) << 3);
      *(u16x8*)&a_lds[idx] = v;
    }
  }
  __syncthreads();

  int wave = tid >> 6, lane = tid & 63;
  int r0 = (wave & 3) * 16, c0 = (wave >> 2) * 256;
  f32x4 acc[16];
#pragma unroll
  for (int n = 0; n < 16; ++n) acc[n] = (f32x4){0.f, 0.f, 0.f, 0.f};
  int arow = r0 + (lane & 15);

  for (int kt = 0; kt < 16; ++kt) {
    int aidx = (arow * 512 + kt * 32 + (lane >> 4) * 8) ^ ((arow & 7) << 3);
    bf16x8 a = ld_frag(&a_lds[aidx]);
    const unsigned short* bp = fragB + ((size_t)(kt * 32 + (c0 >> 4)) * 64 + lane) * 8;
#pragma unroll
    for (int n = 0; n < 16; ++n) {
      bf16x8 b = ld_frag(bp + (size_t)n * 512);
      acc[n] = __builtin_amdgcn_mfma_f32_16x16x32_bf16(a, b, acc[n], 0, 0, 0);
    }
  }

#pragma unroll
  for (int n = 0; n < 16; ++n) {
    int col = c0 + n * 16 + (lane & 15);
#pragma unroll
    for (int reg = 0; reg < 4; ++reg) {
      long row = bt0 + r0 + (lane >> 4) * 4 + reg;
      float v = acc[n][reg];
      if (MODE == 0) {
        int t = (int)(row & (NT - 1));
        long b = row >> 11;
        v += (t == 0) ? (bias_t0[col] + z0[b * NH + col]) : bias_t[col];
        ((unsigned short*)out)[row * 1024 + pre_idx(col)] = f2bf(v);
      } else {
        v += bout[col];
        out[row * 512 + col] = v;
        if ((row & (NT - 1)) == NT - 1) last[(row >> 11) * 512 + col] = v;
      }
    }
  }
}

// ---------------- sequential scan ----------------
// grid 4 x 512 threads; WG w owns batches [16w, 16w+16). No inter-WG sync.
// Wc fully AGPR-resident (256/wave). LDS = 32KB h dbuf only.
__global__ __launch_bounds__(512, 2) void k_scan(float* __restrict__ buf,
                                                 const unsigned short* __restrict__ fragWc) {
  __shared__ __align__(16) unsigned short h_lds[2][16 * 512];   // 32KB
  unsigned short* hbuf = (unsigned short*)buf;
  const int tid = threadIdx.x;
  const int b0 = blockIdx.x * 16;
  const int wave = tid >> 6, lane = tid & 63;
  const int arow = lane & 15, bb = lane >> 4;
  const int c0 = wave * 64;
  const int swz = (arow & 7) << 3;
  const int w2 = wave >> 1;
  const int poff = w2 * 128 + ((w2 >> 1) << 9) + arow * 8 + (wave & 1) * 4;

  const unsigned short* bW = fragWc + ((size_t)(wave * 4) * 64 + lane) * 8;

  // ---- Wc kt=0..15 -> AGPRs (256/wave). "+a" pins in the AGPR file; AGPR
  //      contents can't be rematerialized as loop-invariant L2 loads (the
  //      mechanism that verifiably engaged in R9: FETCH halved).
  f32x4 ba[16][4];
#pragma unroll
  for (int g = 0; g < 16; ++g)
#pragma unroll
    for (int n = 0; n < 4; ++n) ba[g][n] = ld_frag4(bW + (size_t)(g * 32 + n) * 512);
#pragma unroll
  for (int g = 0; g < 16; ++g)
#pragma unroll
    for (int n = 0; n < 4; ++n) asm volatile("" : "+a"(ba[g][n]));

  // ---- t = 0: h0 = tanh(pre0). pre region [0,256)+[768,1024) is disjoint
  //      from the h region [256,768), so no read/write hazard, no barrier.
  u16x4 pr[4];
#pragma unroll
  for (int r = 0; r < 4; ++r)
    pr[r] = *(const u16x4*)(hbuf + (size_t)(b0 + bb * 4 + r) * (size_t)(NT * 1024) + poff);
#pragma unroll
  for (int r = 0; r < 4; ++r)
#pragma unroll
    for (int n = 0; n < 4; ++n) {
      float h = fast_tanh(bf2f(pr[r][n]));
      unsigned short hb = f2bf(h);
      int b = bb * 4 + r, col = c0 + n * 16 + arow;
      hbuf[(size_t)(b0 + b) * (size_t)(NT * 1024) + 256 + col] = hb;
      h_lds[0][(b * 512 + col) ^ ((b & 7) << 3)] = hb;
    }

  // per-lane global pointers at the t=1 row
  const unsigned short* pPre[4];
  unsigned short* pSt[4];
#pragma unroll
  for (int r = 0; r < 4; ++r) {
    size_t base = (size_t)(b0 + bb * 4 + r) * (size_t)(NT * 1024) + 1024;
    pPre[r] = hbuf + base + poff;
    pSt[r]  = hbuf + base + 256 + c0 + arow;
  }
  // preload pre(t=1)
#pragma unroll
  for (int r = 0; r < 4; ++r) pr[r] = *(const u16x4*)pPre[r];

  __syncthreads();  // h_lds[0] visible to all waves

#define AIDX(k) ((arow * 512 + (k) * 32 + bb * 8) ^ swz)
#define AGPR_STEP(G)                                                            \
  {                                                                             \
    bf16x8 a = ld_frag(hs + AIDX(G));                                           \
    _Pragma("unroll") for (int n = 0; n < 4; ++n)                               \
        acc[n] = __builtin_amdgcn_mfma_f32_16x16x32_bf16(                       \
            a, __builtin_bit_cast(bf16x8, ba[G][n]), acc[n], 0, 0, 0);          \
  }

#pragma unroll 1
  for (int t = 1; t < NT; ++t) {
    // acc <- pre(t); then immediately issue pre(t+1) loads (the full MFMA
    // phase + barrier hides them; raw barrier won't drain vmcnt)
    f32x4 acc[4];
#pragma unroll
    for (int n = 0; n < 4; ++n)
#pragma unroll
      for (int r = 0; r < 4; ++r) acc[n][r] = bf2f(pr[r][n]);
    if (t < NT - 1) {
#pragma unroll
      for (int r = 0; r < 4; ++r) {
        pPre[r] += 1024;
        pr[r] = *(const u16x4*)pPre[r];
      }
    }

    const unsigned short* hs = h_lds[(t - 1) & 1];

    // 16 x {ds_read A-frag, 4 MFMA} -- all B operands AGPR-resident
    AGPR_STEP(0)  AGPR_STEP(1)  AGPR_STEP(2)  AGPR_STEP(3)
    AGPR_STEP(4)  AGPR_STEP(5)  AGPR_STEP(6)  AGPR_STEP(7)
    AGPR_STEP(8)  AGPR_STEP(9)  AGPR_STEP(10) AGPR_STEP(11)
    AGPR_STEP(12) AGPR_STEP(13) AGPR_STEP(14) AGPR_STEP(15)

    // epilogue: tanh -> bf16 h -> global (P3 input) + LDS (next step's A)
    unsigned short* hdst = h_lds[t & 1];
#pragma unroll
    for (int n = 0; n < 4; ++n)
#pragma unroll
      for (int r = 0; r < 4; ++r) {
        int b = bb * 4 + r;
        float h = fast_tanh(acc[n][r]);
        unsigned short hb = f2bf(h);
        pSt[r][n * 16] = hb;
        hdst[(b * 512 + c0 + n * 16 + arow) ^ ((b & 7) << 3)] = hb;
      }
#pragma unroll
    for (int r = 0; r < 4; ++r) pSt[r] += 1024;

    // lgkm-only drain + raw barrier: LDS h-exchange synced; global loads/stores
    // (pre prefetch, h stores) stay in flight across the step boundary.
    asm volatile("s_waitcnt lgkmcnt(0)" ::: "memory");
    __builtin_amdgcn_s_barrier();
    asm volatile("" ::: "memory");
  }
#undef AGPR_STEP
#undef AIDX
}

// ---------------- launch ----------------
extern "C" void kernel_launch(void* const* d_in, const int* in_sizes, int n_in,
                              void* d_out, int out_size, void* d_ws, size_t ws_size,
                              hipStream_t stream) {
  const float* emb  = (const float*)d_in[0];
  const float* ll   = (const float*)d_in[1];
  const float* Whx  = (const float*)d_in[2];
  const float* bhx  = (const float*)d_in[3];
  const float* Wyh  = (const float*)d_in[4];
  const float* byh  = (const float*)d_in[5];
  const float* Wout = (const float*)d_in[6];
  const float* bout = (const float*)d_in[7];

  float* buf  = (float*)d_out;                       // [B*T, 512] pre/h -> y (in place)
  float* last = buf + (size_t)NB * NT * NO;          // [B, O] tail

  char* ws = (char*)d_ws;                            // ~2.7 MB used
  unsigned short* fragWhx  = (unsigned short*)ws;                         // 512KB
  unsigned short* fragWc   = (unsigned short*)(ws + (512 * 512 * 2));     // 512KB
  unsigned short* fragWout = (unsigned short*)(ws + 2 * (512 * 512 * 2)); // 512KB
  float* z0      = (float*)(ws + 3 * (512 * 512 * 2));                    // 128KB
  float* bias_t0 = z0 + NB * NH;
  float* bias_t  = bias_t0 + NH;
  float* Wc_f32  = bias_t + NH;                                           // 1MB

  k_bias<<<1, 512, 0, stream>>>(Wyh, bout, bhx, byh, bias_t0, bias_t);
  k_z0<<<64, 512, 0, stream>>>(ll, Wyh, z0);
  k_wc<<<512, 512, 0, stream>>>(Wyh, Wout, Wc_f32);
  k_frag<<<128, 256, 0, stream>>>(Whx, fragWhx);     // Bm[d][j] = Whx[j][d]
  k_frag<<<128, 256, 0, stream>>>(Wc_f32, fragWc);   // Bm[k][j] = Wc[j][k]
  k_frag<<<128, 256, 0, stream>>>(Wout, fragWout);   // Bm[k][o] = Wout[o][k]

  // P1: pre = emb @ Whx^T + biases -> bf16 permuted layout (t==0 rows get z0)
  k_gemm<0><<<2048, 512, 0, stream>>>(emb, fragWhx, buf, bias_t0, bias_t, z0, bout, last);
  // P2: sequential scan, h (bf16) written into u16 [256,768) of each row
  k_scan<<<4, 512, 0, stream>>>(buf, fragWc);
  // P3: y = h @ Wout^T + bout, in place; also fills `last`
  k_gemm<1><<<2048, 512, 0, stream>>>(buf, fragWout, buf, bias_t0, bias_t, z0, bout, last);
}

// Round 12
// 7682.470 us; speedup vs baseline: 2.3147x; 2.0085x over previous
//
#include <hip/hip_runtime.h>
#include <hip/hip_bf16.h>

// Jordan RNN restructured:
//   Wc = Wyh @ Wout  [H,H]
//   pre[b,t,:] = emb@Whx^T + bhx + byh + (t==0 ? last_logits@Wyh^T : Wyh@bout)
//   scan: h_t = tanh(pre_t + h_{t-1} @ Wc^T)     (per-batch independent)
//   y_t  = h_t @ Wout^T + bout                    (time-parallel epilogue GEMM)
//
// REGISTER LAW (learned R9/R11): at __launch_bounds__(512,2) the unified
// VGPR+AGPR budget is 256/wave TOTAL. Demand > 256 => scratch spill of the
// "pinned" values (FETCH stays flat because scratch is L2-cached) => 2x
// regression (R11: 384 demanded). Pins hold iff demand <= 256.
//
// Scan: 4 WGs x 512 thd (8 waves, 2/SIMD). Wc placement, demand ~240:
//   kt 0..6   AGPR-resident (7 x 16 = 112 AGPR, "+a"-pinned, under budget)
//   kt 7..12  streamed from L2, 3-buffer rotation (6%3==0 stable mapping)
//   kt 13..15 LDS-resident (96KB) + 32KB h dbuf = 128KB (proven size)
// Steady L2 traffic/step: 192KB Wc + 16KB pre + 16KB h ~= 224KB ~= 4.1k cy
// at 56B/cy/CU -- the predicted step floor (L2-BW bound).
// h(t-1) global store VECTORIZED: 2 x u16x8 per thread from h_lds at step
// top (1KB/wave contiguous) instead of 16 scattered 2B stores.
//
// d_out row layout (1024 u16 per [b,t] row), in-place through all phases:
//   u16 [0,256)+[768,1024) : pre as bf16, permuted (P1 writes; scan reads u16x4)
//   u16 [256,768)          : h as bf16 (scan writes, P3 reads)
//   P3 overwrites the whole row with fp32 y.

#define NB 64
#define NT 2048
#define ND 512
#define NH 512
#define NO 512
#define TH (NT * NH)

typedef float f32x4 __attribute__((ext_vector_type(4)));
typedef __bf16 bf16x8 __attribute__((ext_vector_type(8)));
typedef unsigned short u16x8 __attribute__((ext_vector_type(8)));
typedef unsigned short u16x4 __attribute__((ext_vector_type(4)));

__device__ __forceinline__ unsigned short f2bf(float x) {
  unsigned u = __builtin_bit_cast(unsigned, x);
  u += 0x7FFFu + ((u >> 16) & 1u);               // RNE
  return (unsigned short)(u >> 16);
}
__device__ __forceinline__ float bf2f(unsigned short u) {
  return __builtin_bit_cast(float, (unsigned)u << 16);
}
__device__ __forceinline__ bf16x8 ld_frag(const unsigned short* p) {
  u16x8 r = *(const u16x8*)p;
  return __builtin_bit_cast(bf16x8, r);
}
__device__ __forceinline__ f32x4 ld_frag4(const unsigned short* p) {
  return *(const f32x4*)p;
}
// tanh via hardware exp2/rcp: abs err ~1e-6, inf-safe.
__device__ __forceinline__ float fast_tanh(float x) {
  float ax = __builtin_fabsf(x);
  float e = __builtin_amdgcn_exp2f(ax * 2.8853900817779268f);  // e^(2|x|)
  float r = 1.0f - 2.0f * __builtin_amdgcn_rcpf(e + 1.0f);
  return __builtin_copysignf(r, x);
}

// ---------------- prep kernels ----------------

__global__ void k_bias(const float* __restrict__ Wyh, const float* __restrict__ bout,
                       const float* __restrict__ bhx, const float* __restrict__ byh,
                       float* bias_t0, float* bias_t) {
  int j = threadIdx.x;
  const float* row = Wyh + j * NO;
  float acc = 0.f;
  for (int o = 0; o < NO; ++o) acc += row[o] * bout[o];
  bias_t0[j] = bhx[j] + byh[j];
  bias_t[j]  = bhx[j] + byh[j] + acc;
}

__global__ void k_z0(const float* __restrict__ ll, const float* __restrict__ Wyh,
                     float* z0) {
  int b = blockIdx.x, j = threadIdx.x;
  const float* row = Wyh + j * NO;
  const float* lr = ll + b * NO;
  float acc = 0.f;
  for (int o = 0; o < NO; ++o) acc += lr[o] * row[o];
  z0[b * NH + j] = acc;
}

__global__ void k_wc(const float* __restrict__ Wyh, const float* __restrict__ Wout,
                     float* Wc) {
  int j = blockIdx.x, k = threadIdx.x;
  float acc = 0.f;
  for (int o = 0; o < NO; ++o) acc += Wyh[j * NO + o] * Wout[o * NH + k];
  Wc[j * NH + k] = acc;
}

// Build MFMA B-operand fragments for Bm = src^T (src is [N=512 rows][K=512 cols]).
// Fragment for 16x16x32: lane l holds B[kt*32 + (l>>4)*8 + i][nt*16 + (l&15)], i=0..7.
__global__ void k_frag(const float* __restrict__ src, unsigned short* __restrict__ dst) {
  int gid = blockIdx.x * 256 + threadIdx.x;  // 32768 total
  int lane = gid & 63, tidx = gid >> 6;
  int nt = tidx & 31, kt = tidx >> 5;
  const float* s = src + (size_t)(nt * 16 + (lane & 15)) * 512 + kt * 32 + (lane >> 4) * 8;
  unsigned short* d = dst + (size_t)gid * 8;
#pragma unroll
  for (int i = 0; i < 8; ++i) d[i] = f2bf(s[i]);
}

// permuted pre u16 index within a 1024-u16 row, for hidden col c:
// region base = (c>>7)*128 + ((c>>8)<<9); within: (c&15)*8 + ((c>>4)&7)
// -> regions [0,128),[128,256),[768,896),[896,1024); h keeps [256,768).
__device__ __forceinline__ int pre_idx(int col) {
  int w = col >> 7;
  return w * 128 + ((w >> 1) << 9) + (col & 15) * 8 + ((col >> 4) & 7);
}

// ---------------- big GEMM (P1 and P3) ----------------
// MODE 0 (P1): A fp32 (emb); out = bf16 pre in permuted u16 layout
// MODE 1 (P3): A bf16 h at u16 [256,768) of each row; out = fp32 y (full row);
//              in-place (A aliases out); t==T-1 rows -> last[]
template <int MODE>
__global__ __launch_bounds__(512) void k_gemm(
    const void* __restrict__ Ain, const unsigned short* __restrict__ fragB,
    float* __restrict__ out, const float* __restrict__ bias_t0,
    const float* __restrict__ bias_t, const float* __restrict__ z0,
    const float* __restrict__ bout, float* __restrict__ last) {
  __shared__ __align__(16) unsigned short a_lds[64 * 512];  // 64KB, XOR-swizzled bf16
  int tid = threadIdx.x;
  long bt0 = (long)blockIdx.x * 64;

  if (MODE == 0) {
    const float* A = (const float*)Ain;
#pragma unroll
    for (int it = 0; it < 16; ++it) {
      int chunk = it * 512 + tid;
      int r = chunk >> 7, c4 = chunk & 127;
      float4 v = ((const float4*)A)[(bt0 + r) * 128 + c4];
      int idx = (r * 512 + c4 * 4) ^ ((r & 7) << 3);
      unsigned short* p = &a_lds[idx];
      p[0] = f2bf(v.x); p[1] = f2bf(v.y); p[2] = f2bf(v.z); p[3] = f2bf(v.w);
    }
  } else {
    const unsigned short* A = (const unsigned short*)Ain;
#pragma unroll
    for (int it = 0; it < 8; ++it) {
      int chunk = it * 512 + tid;           // 4096 chunks of 8 u16
      int r = chunk >> 6, c8 = chunk & 63;
      u16x8 v = *(const u16x8*)(A + (size_t)(bt0 + r) * 1024 + 256 + c8 * 8);
      int idx = (r * 512 + c8 * 8) ^ ((r & 7) << 3);
      *(u16x8*)&a_lds[idx] = v;
    }
  }
  __syncthreads();

  int wave = tid >> 6, lane = tid & 63;
  int r0 = (wave & 3) * 16, c0 = (wave >> 2) * 256;
  f32x4 acc[16];
#pragma unroll
  for (int n = 0; n < 16; ++n) acc[n] = (f32x4){0.f, 0.f, 0.f, 0.f};
  int arow = r0 + (lane & 15);

  for (int kt = 0; kt < 16; ++kt) {
    int aidx = (arow * 512 + kt * 32 + (lane >> 4) * 8) ^ ((arow & 7) << 3);
    bf16x8 a = ld_frag(&a_lds[aidx]);
    const unsigned short* bp = fragB + ((size_t)(kt * 32 + (c0 >> 4)) * 64 + lane) * 8;
#pragma unroll
    for (int n = 0; n < 16; ++n) {
      bf16x8 b = ld_frag(bp + (size_t)n * 512);
      acc[n] = __builtin_amdgcn_mfma_f32_16x16x32_bf16(a, b, acc[n], 0, 0, 0);
    }
  }

#pragma unroll
  for (int n = 0; n < 16; ++n) {
    int col = c0 + n * 16 + (lane & 15);
#pragma unroll
    for (int reg = 0; reg < 4; ++reg) {
      long row = bt0 + r0 + (lane >> 4) * 4 + reg;
      float v = acc[n][reg];
      if (MODE == 0) {
        int t = (int)(row & (NT - 1));
        long b = row >> 11;
        v += (t == 0) ? (bias_t0[col] + z0[b * NH + col]) : bias_t[col];
        ((unsigned short*)out)[row * 1024 + pre_idx(col)] = f2bf(v);
      } else {
        v += bout[col];
        out[row * 512 + col] = v;
        if ((row & (NT - 1)) == NT - 1) last[(row >> 11) * 512 + col] = v;
      }
    }
  }
}

// ---------------- sequential scan ----------------
// grid 4 x 512 threads; WG w owns batches [16w, 16w+16). No inter-WG sync.
__global__ __launch_bounds__(512, 2) void k_scan(float* __restrict__ buf,
                                                 const unsigned short* __restrict__ fragWc) {
  __shared__ __align__(16) unsigned short h_lds[2][16 * 512];   // 32KB
  __shared__ __align__(16) unsigned short wc_lds[8 * 12 * 512]; // 96KB: kt13..15
  unsigned short* hbuf = (unsigned short*)buf;
  const int tid = threadIdx.x;
  const int b0 = blockIdx.x * 16;
  const int wave = tid >> 6, lane = tid & 63;
  const int arow = lane & 15, bb = lane >> 4;
  const int c0 = wave * 64;
  const int swz = (arow & 7) << 3;
  const int w2 = wave >> 1;
  const int poff = w2 * 128 + ((w2 >> 1) << 9) + arow * 8 + (wave & 1) * 4;

  const unsigned short* bW = fragWc + ((size_t)(wave * 4) * 64 + lane) * 8;

  // ---- Wc kt=13..15 -> LDS (once) ----
#pragma unroll
  for (int g = 0; g < 3; ++g)
#pragma unroll
    for (int n = 0; n < 4; ++n) {
      f32x4 v = ld_frag4(bW + (size_t)((13 + g) * 32 + n) * 512);
      *(f32x4*)&wc_lds[(size_t)((wave * 3 + g) * 4 + n) * 512 + lane * 8] = v;
    }

  // ---- Wc kt=0..6 -> AGPRs (112/wave, "+a"-pinned). Total demand ~240 <= 256
  //      so the allocator has no reason to spill: pins actually hold.
  f32x4 ba[7][4];
#pragma unroll
  for (int g = 0; g < 7; ++g)
#pragma unroll
    for (int n = 0; n < 4; ++n) ba[g][n] = ld_frag4(bW + (size_t)(g * 32 + n) * 512);
#pragma unroll
  for (int g = 0; g < 7; ++g)
#pragma unroll
    for (int n = 0; n < 4; ++n) asm volatile("" : "+a"(ba[g][n]));

  // ---- t = 0: h0 = tanh(pre0) -> h_lds only (global h0 store happens
  //      vectorized at the top of step t=1; no pre/h aliasing to worry about).
  u16x4 pr[4];
#pragma unroll
  for (int r = 0; r < 4; ++r)
    pr[r] = *(const u16x4*)(hbuf + (size_t)(b0 + bb * 4 + r) * (size_t)(NT * 1024) + poff);
#pragma unroll
  for (int r = 0; r < 4; ++r)
#pragma unroll
    for (int n = 0; n < 4; ++n) {
      float h = fast_tanh(bf2f(pr[r][n]));
      int b = bb * 4 + r, col = c0 + n * 16 + arow;
      h_lds[0][(b * 512 + col) ^ ((b & 7) << 3)] = f2bf(h);
    }

  // per-lane pre pointers at the t=1 row
  const unsigned short* pPre[4];
#pragma unroll
  for (int r = 0; r < 4; ++r)
    pPre[r] = hbuf + (size_t)(b0 + bb * 4 + r) * (size_t)(NT * 1024) + 1024 + poff;
#pragma unroll
  for (int r = 0; r < 4; ++r) pr[r] = *(const u16x4*)pPre[r];

  // vectorized h-store assignment: thread covers 16B chunks tid and tid+512
  // of the 16KB h tile (16 rows x 512 u16). chunk c -> row c>>6, col8 c&63.
  const int bA = tid >> 6, c8A = tid & 63;        // bA = wave, rows 0..7
  const int bB = bA + 8;                          // rows 8..15
  const int ldsA = (bA * 512 + c8A * 8) ^ ((bA & 7) << 3);
  const int ldsB = (bB * 512 + c8A * 8) ^ ((bB & 7) << 3);
  unsigned short* pHA =
      hbuf + (size_t)(b0 + bA) * (size_t)(NT * 1024) + 256 + c8A * 8;  // t=0 row
  unsigned short* pHB =
      hbuf + (size_t)(b0 + bB) * (size_t)(NT * 1024) + 256 + c8A * 8;

  // stream prologue: q0<-kt7, q1<-kt8, q2<-kt9
  bf16x8 q0[4], q1[4], q2[4];
#pragma unroll
  for (int n = 0; n < 4; ++n) q0[n] = ld_frag(bW + (size_t)(7 * 32 + n) * 512);
#pragma unroll
  for (int n = 0; n < 4; ++n) q1[n] = ld_frag(bW + (size_t)(8 * 32 + n) * 512);
#pragma unroll
  for (int n = 0; n < 4; ++n) q2[n] = ld_frag(bW + (size_t)(9 * 32 + n) * 512);

  __syncthreads();  // h_lds[0] + wc_lds visible to all waves

#define AIDX(k) ((arow * 512 + (k) * 32 + bb * 8) ^ swz)
#define AGPR_STEP(G)                                                            \
  {                                                                             \
    bf16x8 a = ld_frag(hs + AIDX(G));                                           \
    _Pragma("unroll") for (int n = 0; n < 4; ++n)                               \
        acc[n] = __builtin_amdgcn_mfma_f32_16x16x32_bf16(                       \
            a, __builtin_bit_cast(bf16x8, ba[G][n]), acc[n], 0, 0, 0);          \
  }
#define STREAM_STEP(Q, KT, RKT)                                                 \
  {                                                                             \
    bf16x8 a = ld_frag(hs + AIDX(KT));                                          \
    _Pragma("unroll") for (int n = 0; n < 4; ++n)                               \
        acc[n] = __builtin_amdgcn_mfma_f32_16x16x32_bf16(a, Q[n], acc[n], 0, 0, 0); \
    _Pragma("unroll") for (int n = 0; n < 4; ++n)                               \
        Q[n] = ld_frag(bWs + (size_t)((RKT) * 32 + n) * 512);                   \
  }
#define LDS_STEP(G)                                                             \
  {                                                                             \
    bf16x8 a = ld_frag(hs + AIDX(13 + G));                                      \
    _Pragma("unroll") for (int n = 0; n < 4; ++n) {                             \
      bf16x8 b = ld_frag(&wc_lds[(size_t)((wave * 3 + (G)) * 4 + n) * 512 + lane * 8]); \
      acc[n] = __builtin_amdgcn_mfma_f32_16x16x32_bf16(a, b, acc[n], 0, 0, 0);  \
    }                                                                           \
  }

#pragma unroll 1
  for (int t = 1; t < NT; ++t) {
    // launder the stream base pointer so LICM can't hoist the reissue loads
    const unsigned short* bWs = bW;
    asm volatile("" : "+v"(bWs));

    const unsigned short* hs = h_lds[(t - 1) & 1];

    // vectorized h(t-1) -> global: 2 x 16B coalesced per thread (1KB/wave).
    // h_lds[(t-1)&1] is stable all of step t; stores ride the VMEM queue
    // across the raw barrier (no vmcnt drain).
    {
      u16x8 hA = *(const u16x8*)&hs[ldsA];
      u16x8 hB = *(const u16x8*)&hs[ldsB];
      *(u16x8*)pHA = hA;
      *(u16x8*)pHB = hB;
      pHA += 1024; pHB += 1024;
    }

    f32x4 acc[4];
#pragma unroll
    for (int n = 0; n < 4; ++n)
#pragma unroll
      for (int r = 0; r < 4; ++r) acc[n][r] = bf2f(pr[r][n]);

    // AGPR phase (kt 0..6) -- covers the prologue/reissue flight time
    AGPR_STEP(0) AGPR_STEP(1) AGPR_STEP(2) AGPR_STEP(3)
    AGPR_STEP(4) AGPR_STEP(5) AGPR_STEP(6)
    // streamed (kt 7..12, stable 3-buffer rotation) interleaved with LDS
    STREAM_STEP(q0, 7, 10)
    STREAM_STEP(q1, 8, 11)
    STREAM_STEP(q2, 9, 12)
    LDS_STEP(0)
    STREAM_STEP(q0, 10, 7)   // reissues land for step t+1
    LDS_STEP(1)
    STREAM_STEP(q1, 11, 8)
    LDS_STEP(2)
    STREAM_STEP(q2, 12, 9)

    // pre(t+1): issued AFTER all stream loads (in-order vmcnt safety)
    if (t < NT - 1) {
#pragma unroll
      for (int r = 0; r < 4; ++r) {
        pPre[r] += 1024;
        pr[r] = *(const u16x4*)pPre[r];
      }
    }

    // epilogue: tanh -> bf16 -> h_lds only (global store happens next step)
    unsigned short* hdst = h_lds[t & 1];
#pragma unroll
    for (int n = 0; n < 4; ++n)
#pragma unroll
      for (int r = 0; r < 4; ++r) {
        int b = bb * 4 + r;
        float h = fast_tanh(acc[n][r]);
        hdst[(b * 512 + c0 + n * 16 + arow) ^ ((b & 7) << 3)] = f2bf(h);
      }

    // lgkm-only drain + raw barrier: LDS h-exchange synced; global traffic
    // (stream reissues, pre prefetch, h stores) stays in flight across steps.
    asm volatile("s_waitcnt lgkmcnt(0)" ::: "memory");
    __builtin_amdgcn_s_barrier();
    asm volatile("" ::: "memory");
  }

  // tail: store h(NT-1) (the loop stores h(t-1) at the top of step t)
  {
    const unsigned short* hs = h_lds[(NT - 1) & 1];
    u16x8 hA = *(const u16x8*)&hs[ldsA];
    u16x8 hB = *(const u16x8*)&hs[ldsB];
    *(u16x8*)pHA = hA;
    *(u16x8*)pHB = hB;
  }
#undef LDS_STEP
#undef STREAM_STEP
#undef AGPR_STEP
#undef AIDX
}

// ---------------- launch ----------------
extern "C" void kernel_launch(void* const* d_in, const int* in_sizes, int n_in,
                              void* d_out, int out_size, void* d_ws, size_t ws_size,
                              hipStream_t stream) {
  const float* emb  = (const float*)d_in[0];
  const float* ll   = (const float*)d_in[1];
  const float* Whx  = (const float*)d_in[2];
  const float* bhx  = (const float*)d_in[3];
  const float* Wyh  = (const float*)d_in[4];
  const float* byh  = (const float*)d_in[5];
  const float* Wout = (const float*)d_in[6];
  const float* bout = (const float*)d_in[7];

  float* buf  = (float*)d_out;                       // [B*T, 512] pre/h -> y (in place)
  float* last = buf + (size_t)NB * NT * NO;          // [B, O] tail

  char* ws = (char*)d_ws;                            // ~2.7 MB used
  unsigned short* fragWhx  = (unsigned short*)ws;                         // 512KB
  unsigned short* fragWc   = (unsigned short*)(ws + (512 * 512 * 2));     // 512KB
  unsigned short* fragWout = (unsigned short*)(ws + 2 * (512 * 512 * 2)); // 512KB
  float* z0      = (float*)(ws + 3 * (512 * 512 * 2));                    // 128KB
  float* bias_t0 = z0 + NB * NH;
  float* bias_t  = bias_t0 + NH;
  float* Wc_f32  = bias_t + NH;                                           // 1MB

  k_bias<<<1, 512, 0, stream>>>(Wyh, bout, bhx, byh, bias_t0, bias_t);
  k_z0<<<64, 512, 0, stream>>>(ll, Wyh, z0);
  k_wc<<<512, 512, 0, stream>>>(Wyh, Wout, Wc_f32);
  k_frag<<<128, 256, 0, stream>>>(Whx, fragWhx);     // Bm[d][j] = Whx[j][d]
  k_frag<<<128, 256, 0, stream>>>(Wc_f32, fragWc);   // Bm[k][j] = Wc[j][k]
  k_frag<<<128, 256, 0, stream>>>(Wout, fragWout);   // Bm[k][o] = Wout[o][k]

  // P1: pre = emb @ Whx^T + biases -> bf16 permuted layout (t==0 rows get z0)
  k_gemm<0><<<2048, 512, 0, stream>>>(emb, fragWhx, buf, bias_t0, bias_t, z0, bout, last);
  // P2: sequential scan, h (bf16) written into u16 [256,768) of each row
  k_scan<<<4, 512, 0, stream>>>(buf, fragWc);
  // P3: y = h @ Wout^T + bout, in place; also fills `last`
  k_gemm<1><<<2048, 512, 0, stream>>>(buf, fragWout, buf, bias_t0, bias_t, z0, bout, last);
}